// Round 10
// baseline (882.851 us; speedup 1.0000x reference)
//
#include <hip/hip_runtime.h>

#define N_NODES 100000
#define N_EDGES 1600000
#define IN_CH 128
#define OUT_CH 64
#define NEG_SLOPE 0.2f
#define EPS 1e-16f

// Binning geometry: 98 buckets of 1024 destination nodes each.
#define B_SHIFT 10
#define NB 98                 // ceil(100000 / 1024)
#define CAP 17408             // avg 16327/bucket, sigma~127 -> +8.5 sigma
#define EPB 2048              // edges per k_bin block
#define NBLK_BIN 782          // ceil(1600000 / 2048)

#define PROJ_TILE 64
#define NBLK_PROJ 1563        // ceil(100000 / 64)
#define XPAD 132              // 132 % 32 == 4 -> 2-way bank alias; 528B keeps 16B align

#define CHH 32                // channels per k_agg block (2 blocks/bucket)

// ---------------------------------------------------------------------------
// W transpose: W[64][128] -> Wt[128][64]. 32 KB, ~2 us.
// ---------------------------------------------------------------------------
__global__ __launch_bounds__(256) void k_wt(
    const float* __restrict__ W, float* __restrict__ Wt)
{
    const int tid = blockIdx.x * 256 + threadIdx.x;   // 0..8191
    if (tid < OUT_CH * IN_CH) {
        const int c = tid >> 7;        // /IN_CH
        const int k = tid & (IN_CH - 1);
        Wt[k * OUT_CH + c] = W[tid];
    }
}

// ---------------------------------------------------------------------------
// Kernel 1: h = x @ W^T (+ fused s_src, s_dst), register-tiled GEMM.
// unroll 1 + launch_bounds(256,4) keep VGPR <=128 (Round-6 spill fix).
// ---------------------------------------------------------------------------
__global__ __launch_bounds__(256, 4) void k_proj(
    const float* __restrict__ x, const float* __restrict__ Wt,
    const float* __restrict__ att,
    float* __restrict__ h, float* __restrict__ ssrc, float* __restrict__ sdst)
{
    __shared__ float xs[PROJ_TILE][XPAD];    // 33 KB
    __shared__ float ws[IN_CH][OUT_CH];      // 32 KB
    const int t = threadIdx.x;
    const int gbase = blockIdx.x * PROJ_TILE;

    // Stage Wt: 2048 float4, 8 per thread, coalesced (L2-hot 32 KB).
#pragma unroll
    for (int i = 0; i < 8; ++i) {
        const int f4 = i * 256 + t;
        const int k  = f4 >> 4;                // 16 float4 per row
        const int c0 = (f4 & 15) * 4;
        *reinterpret_cast<float4*>(&ws[k][c0]) =
            *reinterpret_cast<const float4*>(Wt + k * OUT_CH + c0);
    }
    // Stage x tile: 2048 float4, 8 per thread, coalesced; zero-fill tail.
#pragma unroll
    for (int i = 0; i < 8; ++i) {
        const int f4 = i * 256 + t;
        const int n  = f4 >> 5;                // 32 float4 per row
        const int k0 = (f4 & 31) * 4;
        float4 v = make_float4(0.f, 0.f, 0.f, 0.f);
        if (gbase + n < N_NODES)
            v = *reinterpret_cast<const float4*>(
                    x + (size_t)(gbase + n) * IN_CH + k0);
        *reinterpret_cast<float4*>(&xs[n][k0]) = v;
    }
    __syncthreads();

    const int cg = t & 15;          // channel group -> channels cg*4..+3
    const int ng = t >> 4;          // node group    -> nodes ng*4..+3
    const int c0 = cg * 4;

    float acc[4][4];
#pragma unroll
    for (int i = 0; i < 4; ++i)
#pragma unroll
        for (int j = 0; j < 4; ++j) acc[i][j] = 0.f;

#pragma unroll 1
    for (int k4 = 0; k4 < IN_CH / 4; ++k4) {
        float4 xr[4], wr[4];
#pragma unroll
        for (int i = 0; i < 4; ++i)
            xr[i] = *reinterpret_cast<const float4*>(&xs[ng * 4 + i][k4 * 4]);
#pragma unroll
        for (int j = 0; j < 4; ++j)
            wr[j] = *reinterpret_cast<const float4*>(&ws[k4 * 4 + j][c0]);
#pragma unroll
        for (int i = 0; i < 4; ++i) {
#pragma unroll
            for (int j = 0; j < 4; ++j) {
                const float xe = j == 0 ? xr[i].x : j == 1 ? xr[i].y
                               : j == 2 ? xr[i].z : xr[i].w;
                acc[i][0] = fmaf(xe, wr[j].x, acc[i][0]);
                acc[i][1] = fmaf(xe, wr[j].y, acc[i][1]);
                acc[i][2] = fmaf(xe, wr[j].z, acc[i][2]);
                acc[i][3] = fmaf(xe, wr[j].w, acc[i][3]);
            }
        }
    }

    // Epilogue: write h (coalesced float4) + fused attention scores.
    const float as0 = att[c0],          as1 = att[c0 + 1];
    const float as2 = att[c0 + 2],      as3 = att[c0 + 3];
    const float ad0 = att[OUT_CH + c0],     ad1 = att[OUT_CH + c0 + 1];
    const float ad2 = att[OUT_CH + c0 + 2], ad3 = att[OUT_CH + c0 + 3];

#pragma unroll
    for (int i = 0; i < 4; ++i) {
        const int n = gbase + ng * 4 + i;
        if (n < N_NODES) {
            *reinterpret_cast<float4*>(h + (size_t)n * OUT_CH + c0) =
                make_float4(acc[i][0], acc[i][1], acc[i][2], acc[i][3]);
        }
        float ps = acc[i][0] * as0 + acc[i][1] * as1
                 + acc[i][2] * as2 + acc[i][3] * as3;
        float pd = acc[i][0] * ad0 + acc[i][1] * ad1
                 + acc[i][2] * ad2 + acc[i][3] * ad3;
        ps += __shfl_xor(ps, 1); pd += __shfl_xor(pd, 1);
        ps += __shfl_xor(ps, 2); pd += __shfl_xor(pd, 2);
        ps += __shfl_xor(ps, 4); pd += __shfl_xor(pd, 4);
        ps += __shfl_xor(ps, 8); pd += __shfl_xor(pd, 8);
        if (cg == 0 && n < N_NODES) { ssrc[n] = ps; sdst[n] = pd; }
    }
}

// ---------------------------------------------------------------------------
// Pass A: bin edges by coarse destination bucket (col >> 10). Per-block LDS
// histogram + one global atomic per (block,bucket) chunk reservation, then
// chunked scatter of packed (row<<10 | col_local) words (~84B contiguous
// chunks -> full-line writes).
// ---------------------------------------------------------------------------
__global__ __launch_bounds__(256) void k_bin(
    const int* __restrict__ ei, int* __restrict__ gcnt,
    int* __restrict__ gbuckets)
{
    __shared__ int hist[NB], base[NB], offs[NB];
    const int t = threadIdx.x;
    for (int i = t; i < NB; i += 256) hist[i] = 0;
    __syncthreads();

    const int e0 = blockIdx.x * EPB;
#pragma unroll
    for (int i = 0; i < 2; ++i) {
        const int e = e0 + (i * 256 + t) * 4;
        if (e + 4 <= N_EDGES) {
            const int4 c4 = *reinterpret_cast<const int4*>(ei + N_EDGES + e);
            atomicAdd(hist + (c4.x >> B_SHIFT), 1);
            atomicAdd(hist + (c4.y >> B_SHIFT), 1);
            atomicAdd(hist + (c4.z >> B_SHIFT), 1);
            atomicAdd(hist + (c4.w >> B_SHIFT), 1);
        }
    }
    __syncthreads();

    for (int i = t; i < NB; i += 256) {
        base[i] = atomicAdd(gcnt + i, hist[i]);
        offs[i] = 0;
    }
    __syncthreads();

#pragma unroll
    for (int i = 0; i < 2; ++i) {
        const int e = e0 + (i * 256 + t) * 4;
        if (e + 4 <= N_EDGES) {
            const int4 c4 = *reinterpret_cast<const int4*>(ei + N_EDGES + e);
            const int4 r4 = *reinterpret_cast<const int4*>(ei + e);
            int b, p;
            b = c4.x >> B_SHIFT; p = base[b] + atomicAdd(offs + b, 1);
            if (p < CAP) gbuckets[b * CAP + p] = (r4.x << B_SHIFT) | (c4.x & 1023);
            b = c4.y >> B_SHIFT; p = base[b] + atomicAdd(offs + b, 1);
            if (p < CAP) gbuckets[b * CAP + p] = (r4.y << B_SHIFT) | (c4.y & 1023);
            b = c4.z >> B_SHIFT; p = base[b] + atomicAdd(offs + b, 1);
            if (p < CAP) gbuckets[b * CAP + p] = (r4.z << B_SHIFT) | (c4.z & 1023);
            b = c4.w >> B_SHIFT; p = base[b] + atomicAdd(offs + b, 1);
            if (p < CAP) gbuckets[b * CAP + p] = (r4.w << B_SHIFT) | (c4.w & 1023);
        }
    }
}

// ---------------------------------------------------------------------------
// Fused aggregate: one block per (bucket, channel-half). The bucket's 1024
// destination nodes get a 1024x32 fp32 accumulator + denominator in LDS
// (136 KB); the bucket's UNSORTED packed edges are consumed directly from
// gbuckets — no CSR sort, no offsets, no srow/alpha arrays. Per half-wave
// (32 lanes = 32 channels) per edge:
//   alpha = exp(leaky_relu(ssrc[row] + sdst[col]))   (inline, broadcast loads)
//   acc[col][ch] += alpha * h[row][H*32+ch]          (ds_add_f32, bank=ch,
//   den[col]     += alpha  (lane ch==0)               conflict-free)
// Epilogue: out[node][H*32+ch] = acc/(den+EPS), coalesced. Zero-degree
// nodes produce 0. Replaces k_scanb + k_csr + k_gather entirely.
// ---------------------------------------------------------------------------
__global__ __launch_bounds__(1024, 1) void k_agg(
    const int* __restrict__ gbuckets, const int* __restrict__ gcnt,
    const float* __restrict__ h,
    const float* __restrict__ ssrc, const float* __restrict__ sdst,
    float* __restrict__ out)
{
    __shared__ float acc[1024][CHH];   // 128 KB
    __shared__ float den[1024];        // 4 KB
    __shared__ float sdl[1024];        // 4 KB
    const int t = threadIdx.x;
    const int b = blockIdx.x >> 1;     // bucket
    const int H = blockIdx.x & 1;      // channel half
    int cnt = gcnt[b]; if (cnt > CAP) cnt = CAP;
    const int* __restrict__ bucket = gbuckets + (size_t)b * CAP;
    const int gnode0 = b << B_SHIFT;

    const int node = gnode0 + t;
    sdl[t] = (node < N_NODES) ? sdst[node] : 0.f;
    den[t] = 0.f;
    float* accf = &acc[0][0];
    for (int f = t; f < 1024 * CHH; f += 1024) accf[f] = 0.f;
    __syncthreads();

    const int lane = t & 63;
    const int wid  = t >> 6;           // 16 waves
    const int half = lane >> 5;        // which edge of the pair
    const int ch   = lane & 31;
    const int hoff = H * CHH + ch;

    // 2 edges per wave per step, manually 2-unrolled -> 4 gathers in flight.
    int j = wid * 2 + half;
    for (; j + 32 < cnt; j += 64) {
        const int pA = bucket[j];          // broadcast (uniform per half)
        const int pB = bucket[j + 32];
        const int rowA = pA >> B_SHIFT, clA = pA & 1023;
        const int rowB = pB >> B_SHIFT, clB = pB & 1023;
        const float hA = h[(size_t)rowA * OUT_CH + hoff];   // 128B/half
        const float hB = h[(size_t)rowB * OUT_CH + hoff];
        const float sA = ssrc[rowA] + sdl[clA];
        const float sB = ssrc[rowB] + sdl[clB];
        const float aA = __expf(sA > 0.f ? sA : sA * NEG_SLOPE);
        const float aB = __expf(sB > 0.f ? sB : sB * NEG_SLOPE);
        atomicAdd(&acc[clA][ch], aA * hA);
        atomicAdd(&acc[clB][ch], aB * hB);
        if (ch == 0) { atomicAdd(&den[clA], aA); atomicAdd(&den[clB], aB); }
    }
    for (; j < cnt; j += 32) {
        const int p = bucket[j];
        const int row = p >> B_SHIFT, cl = p & 1023;
        const float hv = h[(size_t)row * OUT_CH + hoff];
        const float s = ssrc[row] + sdl[cl];
        const float a = __expf(s > 0.f ? s : s * NEG_SLOPE);
        atomicAdd(&acc[cl][ch], a * hv);
        if (ch == 0) atomicAdd(&den[cl], a);
    }
    __syncthreads();

    // Epilogue: 32 floats per thread; consecutive threads -> consecutive
    // channels -> 128B coalesced segments.
    for (int f = t; f < 1024 * CHH; f += 1024) {
        const int n = f >> 5;
        const int c = f & 31;
        const int gn = gnode0 + n;
        if (gn < N_NODES)
            out[(size_t)gn * OUT_CH + H * CHH + c] = accf[f] / (den[n] + EPS);
    }
}

extern "C" void kernel_launch(void* const* d_in, const int* in_sizes, int n_in,
                              void* d_out, int out_size, void* d_ws, size_t ws_size,
                              hipStream_t stream) {
    const float* x   = (const float*)d_in[0];
    const float* W   = (const float*)d_in[1];
    const float* att = (const float*)d_in[2];
    const int*   ei  = (const int*)d_in[3];
    float* out = (float*)d_out;

    char* ws = (char*)d_ws;
    size_t off = 0;
    auto carve = [&](size_t bytes) {
        void* p = ws + off;
        off += (bytes + 255) & ~(size_t)255;
        return p;
    };
    float* h        = (float*)carve((size_t)N_NODES * OUT_CH * 4);   // 25.6 MB
    float* ssrc     = (float*)carve(N_NODES * 4);
    float* sdst     = (float*)carve(N_NODES * 4);
    float* Wt       = (float*)carve((size_t)IN_CH * OUT_CH * 4);     // 32 KB
    int*   gbuckets = (int*)carve((size_t)NB * CAP * 4);             // 6.8 MB
    int*   gcnt     = (int*)carve(NB * 4);

    hipMemsetAsync(gcnt, 0, NB * sizeof(int), stream);

    k_wt<<<(OUT_CH * IN_CH + 255) / 256, 256, 0, stream>>>(W, Wt);
    k_proj<<<NBLK_PROJ, 256, 0, stream>>>(x, Wt, att, h, ssrc, sdst);
    k_bin<<<NBLK_BIN, 256, 0, stream>>>(ei, gcnt, gbuckets);
    k_agg<<<NB * 2, 1024, 0, stream>>>(gbuckets, gcnt, h, ssrc, sdst, out);
}

// Round 11
// 230.709 us; speedup vs baseline: 3.8267x; 3.8267x over previous
//
#include <hip/hip_runtime.h>

#define N_NODES 100000
#define N_EDGES 1600000
#define IN_CH 128
#define OUT_CH 64
#define NEG_SLOPE 0.2f
#define EPS 1e-16f

// Binning geometry: 392 buckets of 256 destination nodes each.
#define B_SHIFT 8
#define BMASK 255
#define NB 392                // ceil(100000 / 256)
#define CAP 4608              // avg 4082/bucket, sigma~64 -> +8 sigma
#define EPB 4096              // edges per k_bin block
#define NBLK_BIN 391          // ceil(1600000 / 4096)

#define PROJ_TILE 64
#define NBLK_PROJ 1563        // ceil(100000 / 64)
#define XPAD 132              // 132 % 32 == 4 -> 2-way bank alias; 528B keeps 16B align

// ---------------------------------------------------------------------------
// W transpose: W[64][128] -> Wt[128][64]. 32 KB, ~2 us.
// ---------------------------------------------------------------------------
__global__ __launch_bounds__(256) void k_wt(
    const float* __restrict__ W, float* __restrict__ Wt)
{
    const int tid = blockIdx.x * 256 + threadIdx.x;   // 0..8191
    if (tid < OUT_CH * IN_CH) {
        const int c = tid >> 7;        // /IN_CH
        const int k = tid & (IN_CH - 1);
        Wt[k * OUT_CH + c] = W[tid];
    }
}

// ---------------------------------------------------------------------------
// Kernel 1: h = x @ W^T (+ fused s_src, s_dst), register-tiled GEMM.
// unroll 1 + launch_bounds(256,4) keep VGPR <=128 (Round-6 spill fix).
// ---------------------------------------------------------------------------
__global__ __launch_bounds__(256, 4) void k_proj(
    const float* __restrict__ x, const float* __restrict__ Wt,
    const float* __restrict__ att,
    float* __restrict__ h, float* __restrict__ ssrc, float* __restrict__ sdst)
{
    __shared__ float xs[PROJ_TILE][XPAD];    // 33 KB
    __shared__ float ws[IN_CH][OUT_CH];      // 32 KB
    const int t = threadIdx.x;
    const int gbase = blockIdx.x * PROJ_TILE;

    // Stage Wt: 2048 float4, 8 per thread, coalesced (L2-hot 32 KB).
#pragma unroll
    for (int i = 0; i < 8; ++i) {
        const int f4 = i * 256 + t;
        const int k  = f4 >> 4;                // 16 float4 per row
        const int c0 = (f4 & 15) * 4;
        *reinterpret_cast<float4*>(&ws[k][c0]) =
            *reinterpret_cast<const float4*>(Wt + k * OUT_CH + c0);
    }
    // Stage x tile: 2048 float4, 8 per thread, coalesced; zero-fill tail.
#pragma unroll
    for (int i = 0; i < 8; ++i) {
        const int f4 = i * 256 + t;
        const int n  = f4 >> 5;                // 32 float4 per row
        const int k0 = (f4 & 31) * 4;
        float4 v = make_float4(0.f, 0.f, 0.f, 0.f);
        if (gbase + n < N_NODES)
            v = *reinterpret_cast<const float4*>(
                    x + (size_t)(gbase + n) * IN_CH + k0);
        *reinterpret_cast<float4*>(&xs[n][k0]) = v;
    }
    __syncthreads();

    const int cg = t & 15;          // channel group -> channels cg*4..+3
    const int ng = t >> 4;          // node group    -> nodes ng*4..+3
    const int c0 = cg * 4;

    float acc[4][4];
#pragma unroll
    for (int i = 0; i < 4; ++i)
#pragma unroll
        for (int j = 0; j < 4; ++j) acc[i][j] = 0.f;

#pragma unroll 1
    for (int k4 = 0; k4 < IN_CH / 4; ++k4) {
        float4 xr[4], wr[4];
#pragma unroll
        for (int i = 0; i < 4; ++i)
            xr[i] = *reinterpret_cast<const float4*>(&xs[ng * 4 + i][k4 * 4]);
#pragma unroll
        for (int j = 0; j < 4; ++j)
            wr[j] = *reinterpret_cast<const float4*>(&ws[k4 * 4 + j][c0]);
#pragma unroll
        for (int i = 0; i < 4; ++i) {
#pragma unroll
            for (int j = 0; j < 4; ++j) {
                const float xe = j == 0 ? xr[i].x : j == 1 ? xr[i].y
                               : j == 2 ? xr[i].z : xr[i].w;
                acc[i][0] = fmaf(xe, wr[j].x, acc[i][0]);
                acc[i][1] = fmaf(xe, wr[j].y, acc[i][1]);
                acc[i][2] = fmaf(xe, wr[j].z, acc[i][2]);
                acc[i][3] = fmaf(xe, wr[j].w, acc[i][3]);
            }
        }
    }

    // Epilogue: write h (coalesced float4) + fused attention scores.
    const float as0 = att[c0],          as1 = att[c0 + 1];
    const float as2 = att[c0 + 2],      as3 = att[c0 + 3];
    const float ad0 = att[OUT_CH + c0],     ad1 = att[OUT_CH + c0 + 1];
    const float ad2 = att[OUT_CH + c0 + 2], ad3 = att[OUT_CH + c0 + 3];

#pragma unroll
    for (int i = 0; i < 4; ++i) {
        const int n = gbase + ng * 4 + i;
        if (n < N_NODES) {
            *reinterpret_cast<float4*>(h + (size_t)n * OUT_CH + c0) =
                make_float4(acc[i][0], acc[i][1], acc[i][2], acc[i][3]);
        }
        float ps = acc[i][0] * as0 + acc[i][1] * as1
                 + acc[i][2] * as2 + acc[i][3] * as3;
        float pd = acc[i][0] * ad0 + acc[i][1] * ad1
                 + acc[i][2] * ad2 + acc[i][3] * ad3;
        ps += __shfl_xor(ps, 1); pd += __shfl_xor(pd, 1);
        ps += __shfl_xor(ps, 2); pd += __shfl_xor(pd, 2);
        ps += __shfl_xor(ps, 4); pd += __shfl_xor(pd, 4);
        ps += __shfl_xor(ps, 8); pd += __shfl_xor(pd, 8);
        if (cg == 0 && n < N_NODES) { ssrc[n] = ps; sdst[n] = pd; }
    }
}

// ---------------------------------------------------------------------------
// Pass A: bin edges by coarse destination bucket (col >> 8). Per-block LDS
// histogram over 392 buckets + one global atomic per (block,bucket) chunk
// reservation, then chunked scatter of packed (row<<8 | col_local) words.
// ---------------------------------------------------------------------------
__global__ __launch_bounds__(256) void k_bin(
    const int* __restrict__ ei, int* __restrict__ gcnt,
    int* __restrict__ gbuckets)
{
    __shared__ int hist[NB], base[NB], offs[NB];
    const int t = threadIdx.x;
    for (int i = t; i < NB; i += 256) hist[i] = 0;
    __syncthreads();

    const int e0 = blockIdx.x * EPB;
#pragma unroll
    for (int i = 0; i < 4; ++i) {
        const int e = e0 + (i * 256 + t) * 4;
        if (e + 4 <= N_EDGES) {
            const int4 c4 = *reinterpret_cast<const int4*>(ei + N_EDGES + e);
            atomicAdd(hist + (c4.x >> B_SHIFT), 1);
            atomicAdd(hist + (c4.y >> B_SHIFT), 1);
            atomicAdd(hist + (c4.z >> B_SHIFT), 1);
            atomicAdd(hist + (c4.w >> B_SHIFT), 1);
        }
    }
    __syncthreads();

    for (int i = t; i < NB; i += 256) {
        base[i] = atomicAdd(gcnt + i, hist[i]);
        offs[i] = 0;
    }
    __syncthreads();

#pragma unroll
    for (int i = 0; i < 4; ++i) {
        const int e = e0 + (i * 256 + t) * 4;
        if (e + 4 <= N_EDGES) {
            const int4 c4 = *reinterpret_cast<const int4*>(ei + N_EDGES + e);
            const int4 r4 = *reinterpret_cast<const int4*>(ei + e);
            int b, p;
            b = c4.x >> B_SHIFT; p = base[b] + atomicAdd(offs + b, 1);
            if (p < CAP) gbuckets[b * CAP + p] = (r4.x << B_SHIFT) | (c4.x & BMASK);
            b = c4.y >> B_SHIFT; p = base[b] + atomicAdd(offs + b, 1);
            if (p < CAP) gbuckets[b * CAP + p] = (r4.y << B_SHIFT) | (c4.y & BMASK);
            b = c4.z >> B_SHIFT; p = base[b] + atomicAdd(offs + b, 1);
            if (p < CAP) gbuckets[b * CAP + p] = (r4.z << B_SHIFT) | (c4.z & BMASK);
            b = c4.w >> B_SHIFT; p = base[b] + atomicAdd(offs + b, 1);
            if (p < CAP) gbuckets[b * CAP + p] = (r4.w << B_SHIFT) | (c4.w & BMASK);
        }
    }
}

// ---------------------------------------------------------------------------
// Exclusive scan of the 392 bucket counts -> bucket start positions in srow.
// ---------------------------------------------------------------------------
__global__ __launch_bounds__(512) void k_scanb(
    const int* __restrict__ gcnt, int* __restrict__ bstart)
{
    __shared__ int lds[512];
    const int t = threadIdx.x;
    const int v = (t < NB) ? gcnt[t] : 0;
    lds[t] = v;
    __syncthreads();
    for (int off = 1; off < 512; off <<= 1) {
        const int add = (t >= off) ? lds[t - off] : 0;
        __syncthreads();
        lds[t] += add;
        __syncthreads();
    }
    if (t < NB) bstart[t] = lds[t] - v;   // exclusive
}

// ---------------------------------------------------------------------------
// Pass B: one 256-thread block per bucket (392 blocks -> full-machine
// coverage, vs 98 big blocks = 38% of CUs before). LDS histogram over the
// bucket's 256 nodes, shfl wave-scan + 4-entry fixup (2 barriers), emit
// per-node global offsets, then scatter rows into srow (bucket window
// ~18KB -> L2-resident).
// ---------------------------------------------------------------------------
__global__ __launch_bounds__(256) void k_csr(
    const int* __restrict__ gbuckets, const int* __restrict__ gcnt,
    const int* __restrict__ bstart,
    int* __restrict__ offsets, int* __restrict__ srow)
{
    __shared__ int counts[256];
    __shared__ int wsum[4];
    const int t = threadIdx.x;
    const int lane = t & 63;
    const int wid  = t >> 6;
    const int b = blockIdx.x;
    int cnt = gcnt[b]; if (cnt > CAP) cnt = CAP;
    const int bs = bstart[b];
    const int* __restrict__ bucket = gbuckets + (size_t)b * CAP;

    counts[t] = 0;
    __syncthreads();
    for (int j = t; j < cnt; j += 256)
        atomicAdd(counts + (bucket[j] & BMASK), 1);
    __syncthreads();

    // Exclusive scan: shfl inclusive wave-scan + cross-wave fixup.
    const int c = counts[t];
    int v = c;
#pragma unroll
    for (int off = 1; off < 64; off <<= 1) {
        const int u = __shfl_up(v, off);
        if (lane >= off) v += u;
    }
    if (lane == 63) wsum[wid] = v;
    __syncthreads();
    if (t == 0) {
        int a = 0;
#pragma unroll
        for (int i = 0; i < 4; ++i) { const int x = wsum[i]; wsum[i] = a; a += x; }
    }
    __syncthreads();
    const int excl = v + wsum[wid] - c;
    offsets[b * 256 + t] = bs + excl;
    counts[t] = bs + excl;                // reuse as running absolute offsets
    __syncthreads();

    for (int j = t; j < cnt; j += 256) {
        const int p = bucket[j];
        const int pos = atomicAdd(counts + (p & BMASK), 1);
        srow[pos] = p >> B_SHIFT;
    }
}

// ---------------------------------------------------------------------------
// Gather-accumulate (verbatim Round-7 version, measured 65 us): one wave per
// destination node, lane owns channel `lane`.
//   out[c][:] = (sum_j alpha_j * h[row_j][:]) / (sum_j alpha_j + EPS)
// alpha computed inline (traffic-bound kernel -> the VALU work is free).
// ---------------------------------------------------------------------------
__global__ __launch_bounds__(256) void k_gather(
    const int* __restrict__ srow, const int* __restrict__ offsets,
    const float* __restrict__ h,
    const float* __restrict__ ssrc, const float* __restrict__ sdst,
    float* __restrict__ out)
{
    const int lane = threadIdx.x & 63;
    const int c = blockIdx.x * 4 + (threadIdx.x >> 6);
    if (c >= N_NODES) return;

    const int start = __builtin_amdgcn_readfirstlane(offsets[c]);
    const int end   = __builtin_amdgcn_readfirstlane(offsets[c + 1]);
    const float sd = sdst[c];

    float acc0 = 0.f, acc1 = 0.f, acc2 = 0.f, acc3 = 0.f;
    float den0 = 0.f, den1 = 0.f, den2 = 0.f, den3 = 0.f;

    int j = start;
    const int end4 = start + ((end - start) & ~3);
    for (; j < end4; j += 4) {
        const int r0 = __builtin_amdgcn_readfirstlane(srow[j + 0]);
        const int r1 = __builtin_amdgcn_readfirstlane(srow[j + 1]);
        const int r2 = __builtin_amdgcn_readfirstlane(srow[j + 2]);
        const int r3 = __builtin_amdgcn_readfirstlane(srow[j + 3]);

        const float h0 = h[(size_t)r0 * OUT_CH + lane];
        const float h1 = h[(size_t)r1 * OUT_CH + lane];
        const float h2 = h[(size_t)r2 * OUT_CH + lane];
        const float h3 = h[(size_t)r3 * OUT_CH + lane];

        const float s0 = ssrc[r0] + sd;
        const float s1 = ssrc[r1] + sd;
        const float s2 = ssrc[r2] + sd;
        const float s3 = ssrc[r3] + sd;
        const float a0 = __expf(s0 > 0.f ? s0 : s0 * NEG_SLOPE);
        const float a1 = __expf(s1 > 0.f ? s1 : s1 * NEG_SLOPE);
        const float a2 = __expf(s2 > 0.f ? s2 : s2 * NEG_SLOPE);
        const float a3 = __expf(s3 > 0.f ? s3 : s3 * NEG_SLOPE);

        acc0 = fmaf(a0, h0, acc0); den0 += a0;
        acc1 = fmaf(a1, h1, acc1); den1 += a1;
        acc2 = fmaf(a2, h2, acc2); den2 += a2;
        acc3 = fmaf(a3, h3, acc3); den3 += a3;
    }
    for (; j < end; ++j) {
        const int r = __builtin_amdgcn_readfirstlane(srow[j]);
        const float hv = h[(size_t)r * OUT_CH + lane];
        const float s = ssrc[r] + sd;
        const float a = __expf(s > 0.f ? s : s * NEG_SLOPE);
        acc0 = fmaf(a, hv, acc0); den0 += a;
    }

    const float acc = (acc0 + acc1) + (acc2 + acc3);
    const float den = (den0 + den1) + (den2 + den3);
    out[(size_t)c * OUT_CH + lane] = acc / (den + EPS);
}

extern "C" void kernel_launch(void* const* d_in, const int* in_sizes, int n_in,
                              void* d_out, int out_size, void* d_ws, size_t ws_size,
                              hipStream_t stream) {
    const float* x   = (const float*)d_in[0];
    const float* W   = (const float*)d_in[1];
    const float* att = (const float*)d_in[2];
    const int*   ei  = (const int*)d_in[3];
    float* out = (float*)d_out;

    char* ws = (char*)d_ws;
    size_t off = 0;
    auto carve = [&](size_t bytes) {
        void* p = ws + off;
        off += (bytes + 255) & ~(size_t)255;
        return p;
    };
    float* h        = (float*)carve((size_t)N_NODES * OUT_CH * 4);   // 25.6 MB
    float* ssrc     = (float*)carve(N_NODES * 4);
    float* sdst     = (float*)carve(N_NODES * 4);
    float* Wt       = (float*)carve((size_t)IN_CH * OUT_CH * 4);     // 32 KB
    int*   gbuckets = (int*)carve((size_t)NB * CAP * 4);             // 7.2 MB
    int*   gcnt     = (int*)carve(NB * 4);
    int*   bstart   = (int*)carve(NB * 4);
    int*   offsets  = (int*)carve((NB * 256 + 4) * 4);               // 0.4 MB
    int*   srow     = (int*)carve((size_t)N_EDGES * 4);              // 6.4 MB

    hipMemsetAsync(gcnt, 0, NB * sizeof(int), stream);

    k_wt<<<(OUT_CH * IN_CH + 255) / 256, 256, 0, stream>>>(W, Wt);
    k_proj<<<NBLK_PROJ, 256, 0, stream>>>(x, Wt, att, h, ssrc, sdst);
    k_bin<<<NBLK_BIN, 256, 0, stream>>>(ei, gcnt, gbuckets);
    k_scanb<<<1, 512, 0, stream>>>(gcnt, bstart);
    k_csr<<<NB, 256, 0, stream>>>(gbuckets, gcnt, bstart, offsets, srow);
    k_gather<<<(N_NODES + 3) / 4, 256, 0, stream>>>(srow, offsets,
                                                    h, ssrc, sdst, out);
}